// Round 14
// baseline (136.250 us; speedup 1.0000x reference)
//
#include <hip/hip_runtime.h>
#include <hip/hip_bf16.h>

#define B_ROWS 32768

typedef unsigned short u16;
typedef unsigned int u32;
typedef float f32x4 __attribute__((ext_vector_type(4)));
typedef __bf16 bf16x8 __attribute__((ext_vector_type(8)));

__device__ __forceinline__ u16 f2bf(float f){
    union { float f; u32 u; } v; v.f = f;
    return (u16)((v.u + 0x7FFFu + ((v.u >> 16) & 1u)) >> 16);
}
__device__ __forceinline__ float bf2f(u16 h){
    union { u32 u; float f; } v; v.u = ((u32)h) << 16; return v.f;
}
__device__ __forceinline__ u32 cvtpk(float lo, float hi){
    u32 r;
    asm("v_cvt_pk_bf16_f32 %0, %1, %2" : "=v"(r) : "v"(lo), "v"(hi));
    return r;
}
__device__ __forceinline__ void async_cp16(void* lds_dst, const void* g_src){
    __builtin_amdgcn_global_load_lds(
        (const __attribute__((address_space(1))) unsigned int*)g_src,
        (__attribute__((address_space(3))) unsigned int*)lds_dst, 16, 0, 0);
}

// ---------------- weight cast/transpose into staging-friendly images ----------
// pimg : [3][24][4096 u16]  XOR-swizzled proj-B LDS chunk image (BK=32)
// w1img: [8][12 chunks][q:4][col:128][8]
// w2img: [8][4 chunks][q:4][col:128][8]
// prwT : [64][128] plain [o][k]
// gwimg: [16][384] zero-padded gate weights, [e][k]
__global__ void cast_weights_kernel(const float* __restrict__ proj_w,
                                    const float* __restrict__ exp_w1,
                                    const float* __restrict__ exp_w2,
                                    const float* __restrict__ pre_w,
                                    const float* __restrict__ gate_w,
                                    u16* __restrict__ pimg, u16* __restrict__ w1img,
                                    u16* __restrict__ w2img, u16* __restrict__ prwT,
                                    u16* __restrict__ gwimg){
    int i = blockIdx.x * 256 + threadIdx.x;
    if (i < 294912){                       // pimg (BK=32 chunks)
        int m = i / 98304, r = i % 98304;
        int c = r / 4096, rr = r % 4096;
        int col = rr >> 5, kk = rr & 31;
        int kb = kk ^ (((col >> 1) & 3) << 3);
        pimg[i] = f2bf(proj_w[m*98304 + (c*32 + kb)*128 + col]);
    } else if (i < 688128){                // w1img
        int j = i - 294912;
        int e = j / 49152, r = j % 49152;
        int ph = r / 4096, rr = r % 4096;
        int q = rr >> 10, col = (rr >> 3) & 127, el = rr & 7;
        w1img[j] = f2bf(exp_w1[e*49152 + (ph*32 + q*8 + el)*128 + col]);
    } else if (i < 819200){                // w2img
        int j = i - 688128;
        int e = j / 16384, r = j % 16384;
        int c2 = r / 4096, rr = r % 4096;
        int q = rr >> 10, col = (rr >> 3) & 127, el = rr & 7;
        w2img[j] = f2bf(exp_w2[e*16384 + (c2*32 + q*8 + el)*128 + col]);
    } else if (i < 827392){                // prwT
        int j = i - 819200;
        int o = j / 128, k = j % 128;
        prwT[j] = f2bf(pre_w[k*64 + o]);
    } else if (i < 833536){                // gwimg
        int j = i - 827392;
        int e = j / 384, k = j % 384;
        gwimg[j] = (e < 8) ? f2bf(gate_w[k*8 + e]) : (u16)0;
    }
}

// ---------------- fully fused: proj + gate + experts + pre + head -------------
// 256 blocks x 256 threads (4 waves, 2x2), 128 rows/block, 1 block/CU, 160KB LDS.
// Per-wave tile m=4 x n=4 (64x64 quadrant) -> operand duplication 2x/2x
// (was 2x/4x with 8 waves): LDS reads/chunk 64->48 KB (A) / 48->32 KB (C).
#define XS_OFF   0          // 96 KB  x image [half2][kt12][q4][row64][16B]
#define A_OFF    98304      // 3 x 16 KB A-feat ring (phase A)
#define B_OFF    147456     // 2 x 8 KB pimg ring (phase A)
#define HS_OFF   98304      // phase C: 128 x 256B XOR-swizzled = 32768
#define GWT_OFF  131072     // f32 [8][128] = 4096
#define B1_OFF   135168     // bf16 [8][128] = 2048
#define B2_OFF   137216     // bf16 [8][128] = 2048
#define WB_OFF   139264     // 3 x 8 KB expert group buffer -> 163840

__global__ __launch_bounds__(256, 1) void fused_kernel(
    const float* __restrict__ ft, const float* __restrict__ fa, const float* __restrict__ fv,
    const u16* __restrict__ pimg, const float* __restrict__ proj_b,
    const u16* __restrict__ w1img, const u16* __restrict__ w2img,
    const u16* __restrict__ prwT, const u16* __restrict__ gwimg,
    const float* __restrict__ gate_b, const float* __restrict__ exp_b1, const float* __restrict__ exp_b2,
    const float* __restrict__ pre_b, const float* __restrict__ head_w, const float* __restrict__ head_b,
    float* __restrict__ out)
{
    __shared__ __align__(16) char lds[163840];
    const int tid = threadIdx.x;
    const int lane = tid & 63, wid = tid >> 6;   // 4 waves
    const int wr = wid >> 1, wc = wid & 1;       // 2 x 2 (64 rows x 64 cols per wave)
    const int lr = lane & 15, q = lane >> 4;
    const int blk = blockIdx.x;
    const int row0 = blk * 128;
    const char* w1b = (const char*)w1img;
    const char* w2b = (const char*)w2img;
    char* HsB = lds + HS_OFF;
    u16* b1L = (u16*)(lds + B1_OFF);
    u16* b2L = (u16*)(lds + B2_OFF);

    // ---- prologue: proj_b -> registers, drain so pipeline counts are exact ----
    float pb0[4], pb1[4], pb2[4];
    #pragma unroll
    for (int ni = 0; ni < 4; ni++){
        int c = wc*64 + ni*16 + lr;
        pb0[ni] = proj_b[c];
        pb1[ni] = proj_b[128 + c];
        pb2[ni] = proj_b[256 + c];
    }
    asm volatile("s_waitcnt vmcnt(0)" ::: "memory");

    // A staging source offsets (XOR-pre-swizzled global addresses, linear LDS dst)
    u32 aoffs[4];
    #pragma unroll
    for (int i = 0; i < 4; i++){
        int P = i*4096 + tid*16;
        int row = P >> 7, inner = P & 127;
        aoffs[i] = (u32)((row0 + row)*3072 + (inner ^ ((row & 7) << 4)));
    }

#define ASTAGE(c) do{                                                          \
        int mm_ = (c) / 24, kk_ = (c) % 24;                                    \
        const char* ab_ = (const char*)(mm_ == 0 ? ft : mm_ == 1 ? fa : fv);   \
        char* la_ = lds + A_OFF + ((c) % 3)*16384 + tid*16;                    \
        async_cp16(la_,         ab_ + aoffs[0] + kk_*128);                     \
        async_cp16(la_ + 4096,  ab_ + aoffs[1] + kk_*128);                     \
        async_cp16(la_ + 8192,  ab_ + aoffs[2] + kk_*128);                     \
        async_cp16(la_ + 12288, ab_ + aoffs[3] + kk_*128);                     \
    }while(0)

#define BSTAGE(c) do{                                                          \
        int mm_ = (c) / 24, kk_ = (c) % 24;                                    \
        const char* gb_ = (const char*)pimg + mm_*196608 + kk_*8192 + tid*16;  \
        char* lb_ = lds + B_OFF + ((c) % 2)*8192 + tid*16;                     \
        async_cp16(lb_,        gb_);                                           \
        async_cp16(lb_ + 4096, gb_ + 4096);                                    \
    }while(0)

#define PCONSUME(c) do{                                                        \
        const char* Abuf = lds + A_OFF + ((c) % 3)*16384;                      \
        const char* Bbuf = lds + B_OFF + ((c) % 2)*8192;                       \
        bf16x8 af[4];                                                          \
        _Pragma("unroll")                                                      \
        for (int mi = 0; mi < 4; mi++){                                        \
            int row = wr*64 + mi*16 + lr;                                      \
            int aoff = row*128 + ((q*32) ^ ((row & 7) << 4));                  \
            f32x4 a0 = *(const f32x4*)(Abuf + aoff);                           \
            f32x4 a1 = *(const f32x4*)(Abuf + (aoff ^ 16));                    \
            union { u32 w[4]; bf16x8 v; } u;                                   \
            u.w[0] = cvtpk(a0.x, a0.y); u.w[1] = cvtpk(a0.z, a0.w);            \
            u.w[2] = cvtpk(a1.x, a1.y); u.w[3] = cvtpk(a1.z, a1.w);            \
            af[mi] = u.v;                                                      \
        }                                                                      \
        _Pragma("unroll")                                                      \
        for (int ni = 0; ni < 4; ni++){                                        \
            int col = wc*64 + ni*16 + lr;                                      \
            int boff = col*64 + ((q*16) ^ (((col >> 1) & 3) << 4));            \
            bf16x8 bf = *(const bf16x8*)(Bbuf + boff);                         \
            _Pragma("unroll")                                                  \
            for (int mi = 0; mi < 4; mi++)                                     \
                acc[mi][ni] = __builtin_amdgcn_mfma_f32_16x16x32_bf16(af[mi], bf, acc[mi][ni], 0, 0, 0); \
        }                                                                      \
    }while(0)

// one modality: 24 chunk iterations + epilogue into Xs image (MC is a literal)
#define PHASE_A_MOD(MC, PB) do{                                                \
        _Pragma("unroll 1")                                                    \
        for (int kt = 0; kt < 24; kt++){                                       \
            int t = MC*24 + kt;                                                \
            __builtin_amdgcn_sched_barrier(0);                                 \
            __builtin_amdgcn_s_barrier();                                      \
            if (t < 71) BSTAGE(t + 1);                                         \
            if (t < 70) ASTAGE(t + 2);                                         \
            if (t < 70)       asm volatile("s_waitcnt vmcnt(10)" ::: "memory"); \
            else if (t == 70) asm volatile("s_waitcnt vmcnt(6)" ::: "memory"); \
            else              asm volatile("s_waitcnt vmcnt(0)" ::: "memory"); \
            __builtin_amdgcn_s_barrier();                                      \
            __builtin_amdgcn_sched_barrier(0);                                 \
            PCONSUME(t);                                                       \
        }                                                                      \
        _Pragma("unroll")                                                      \
        for (int mi = 0; mi < 4; mi++)                                         \
            _Pragma("unroll")                                                  \
            for (int ni = 0; ni < 4; ni++){                                    \
                int lcol = wc*64 + ni*16 + lr;                                 \
                int colg = MC*128 + lcol;                                      \
                int ktI = colg >> 5, qI = (colg >> 3) & 3, el = colg & 7;      \
                _Pragma("unroll")                                              \
                for (int j = 0; j < 4; j++){                                   \
                    int row = wr*64 + mi*16 + q*4 + j;                         \
                    *(u16*)(lds + (row >> 6)*49152 + ktI*4096 + qI*1024        \
                            + (row & 63)*16 + el*2) = f2bf(acc[mi][ni][j] + PB[ni]); \
                    acc[mi][ni][j] = 0.f;                                      \
                }                                                              \
            }                                                                  \
    }while(0)

    f32x4 acc[4][4];
    #pragma unroll
    for (int i = 0; i < 4; i++)
        #pragma unroll
        for (int j = 0; j < 4; j++) acc[i][j] = {0.f, 0.f, 0.f, 0.f};

    BSTAGE(0); ASTAGE(0); ASTAGE(1);
    PHASE_A_MOD(0, pb0);
    PHASE_A_MOD(1, pb1);
    PHASE_A_MOD(2, pb2);
#undef ASTAGE
#undef BSTAGE
#undef PCONSUME
#undef PHASE_A_MOD

    asm volatile("s_waitcnt lgkmcnt(0)" ::: "memory");
    __builtin_amdgcn_sched_barrier(0);
    __builtin_amdgcn_s_barrier();                          // Xs image complete

    // ---- phase B: group 0 (chunks 0,1,2) prefetch; bias stage; gate ----
    {
        const char* src = w1b + tid*16;
        #pragma unroll
        for (int s = 0; s < 3; s++){
            async_cp16(lds + WB_OFF + s*8192 + tid*16,        src + s*8192);
            async_cp16(lds + WB_OFF + s*8192 + tid*16 + 4096, src + s*8192 + 4096);
        }
    }
    for (int i = tid; i < 1024; i += 256){
        b1L[i] = f2bf(exp_b1[i]);
        b2L[i] = f2bf(exp_b2[i]);
    }
    #pragma unroll
    for (int hr = 0; hr < 2; hr++){
        int g16 = wid*2 + hr;                              // 16-row group 0..7
        f32x4 ga = {0.f, 0.f, 0.f, 0.f};
        const char* xb = lds + (g16 >> 2)*49152 + ((g16 & 3)*16 + lr)*16 + q*1024;
        const u16* gwp = gwimg + lr*384 + q*8;
        #pragma unroll
        for (int kt = 0; kt < 12; kt++){
            bf16x8 af = *(const bf16x8*)(xb + kt*4096);
            bf16x8 gb = *(const bf16x8*)(gwp + kt*32);
            ga = __builtin_amdgcn_mfma_f32_16x16x32_bf16(af, gb, ga, 0, 0, 0);
        }
        float gbv = gate_b[lr & 7];
        float gw4[4];
        #pragma unroll
        for (int j = 0; j < 4; j++){
            float v = ga[j] + gbv;
            float mx = v;
            mx = fmaxf(mx, __shfl_xor(mx, 1));
            mx = fmaxf(mx, __shfl_xor(mx, 2));
            mx = fmaxf(mx, __shfl_xor(mx, 4));
            float s = __expf(v - mx);
            float t = s;
            t += __shfl_xor(t, 1);
            t += __shfl_xor(t, 2);
            t += __shfl_xor(t, 4);
            gw4[j] = s / t;
        }
        if (lr < 8){
            f32x4 wv = {gw4[0], gw4[1], gw4[2], gw4[3]};
            *(f32x4*)(lds + GWT_OFF + lr*512 + (g16*16 + q*4)*4) = wv;
        }
    }
    asm volatile("s_waitcnt vmcnt(0) lgkmcnt(0)" ::: "memory");   // group0+biases+GWT landed
    __builtin_amdgcn_sched_barrier(0);
    __builtin_amdgcn_s_barrier();

    // ---- phase C: 48 groups (per expert: 4x3 w1-chunks + 2x2 w2-chunks) ----
#define WGROUP_STAGE(gg2) do{                                                  \
        int e2_ = (gg2) / 6, i2_ = (gg2) % 6;                                  \
        if (i2_ < 4){                                                          \
            const char* src_ = w1b + e2_*98304 + i2_*24576 + tid*16;           \
            _Pragma("unroll")                                                  \
            for (int s = 0; s < 3; s++){                                       \
                async_cp16(lds + WB_OFF + s*8192 + tid*16,        src_ + s*8192);        \
                async_cp16(lds + WB_OFF + s*8192 + tid*16 + 4096, src_ + s*8192 + 4096); \
            }                                                                  \
        } else {                                                               \
            const char* src_ = w2b + e2_*32768 + (i2_ - 4)*16384 + tid*16;     \
            _Pragma("unroll")                                                  \
            for (int s = 0; s < 2; s++){                                       \
                async_cp16(lds + WB_OFF + s*8192 + tid*16,        src_ + s*8192);        \
                async_cp16(lds + WB_OFF + s*8192 + tid*16 + 4096, src_ + s*8192 + 4096); \
            }                                                                  \
        }                                                                      \
    }while(0)

    f32x4 fus[4][4];
    #pragma unroll
    for (int i = 0; i < 4; i++)
        #pragma unroll
        for (int j = 0; j < 4; j++) fus[i][j] = {0.f, 0.f, 0.f, 0.f};

    #pragma unroll 1
    for (int e = 0; e < 8; e++){
        f32x4 ac1[4][4];
        #pragma unroll
        for (int i = 0; i < 4; i++)
            #pragma unroll
            for (int j = 0; j < 4; j++) ac1[i][j] = {0.f, 0.f, 0.f, 0.f};

        #pragma unroll 1
        for (int grp = 0; grp < 4; grp++){
            #pragma unroll
            for (int c = 0; c < 3; c++){
                int ph = grp*3 + c;
                const char* wsl = lds + WB_OFF + c*8192 + q*2048;
                const char* xa  = lds + wr*49152 + ph*4096 + q*1024;
                bf16x8 af[4];
                #pragma unroll
                for (int mi = 0; mi < 4; mi++)
                    af[mi] = *(const bf16x8*)(xa + (mi*16 + lr)*16);
                #pragma unroll
                for (int ni = 0; ni < 4; ni++){
                    bf16x8 bf = *(const bf16x8*)(wsl + (wc*64 + ni*16 + lr)*16);
                    #pragma unroll
                    for (int mi = 0; mi < 4; mi++)
                        ac1[mi][ni] = __builtin_amdgcn_mfma_f32_16x16x32_bf16(af[mi], bf, ac1[mi][ni], 0, 0, 0);
                }
            }
            if (grp == 3){
                // h = relu(ac1 + b1) -> Hs (XOR-swizzled)
                #pragma unroll
                for (int mi = 0; mi < 4; mi++)
                    #pragma unroll
                    for (int ni = 0; ni < 4; ni++){
                        int col = wc*64 + ni*16 + lr;
                        float b1v = bf2f(b1L[e*128 + col]);
                        #pragma unroll
                        for (int j = 0; j < 4; j++){
                            int row = wr*64 + mi*16 + q*4 + j;
                            *(u16*)(HsB + row*256 + ((col*2) ^ ((row & 7) << 4)))
                                = f2bf(fmaxf(ac1[mi][ni][j] + b1v, 0.f));
                        }
                    }
                asm volatile("s_waitcnt lgkmcnt(0)" ::: "memory");
            }
            __builtin_amdgcn_sched_barrier(0);
            __builtin_amdgcn_s_barrier();                  // WB reads (and Hs writes) done
            WGROUP_STAGE(e*6 + grp + 1);
            asm volatile("s_waitcnt vmcnt(0)" ::: "memory");
            __builtin_amdgcn_s_barrier();                  // next group + Hs visible
            __builtin_amdgcn_sched_barrier(0);
        }

        f32x4 ac2[4][4];
        #pragma unroll
        for (int i = 0; i < 4; i++)
            #pragma unroll
            for (int j = 0; j < 4; j++) ac2[i][j] = {0.f, 0.f, 0.f, 0.f};

        #pragma unroll 1
        for (int grp = 0; grp < 2; grp++){
            #pragma unroll
            for (int c = 0; c < 2; c++){
                int p2 = grp*2 + c;
                const char* wsl = lds + WB_OFF + c*8192 + q*2048;
                int cb = p2*64 + q*16;
                bf16x8 af[4];
                #pragma unroll
                for (int mi = 0; mi < 4; mi++){
                    int rowA = wr*64 + mi*16 + lr;
                    af[mi] = *(const bf16x8*)(HsB + rowA*256 + (cb ^ ((rowA & 7) << 4)));
                }
                #pragma unroll
                for (int ni = 0; ni < 4; ni++){
                    bf16x8 bf = *(const bf16x8*)(wsl + (wc*64 + ni*16 + lr)*16);
                    #pragma unroll
                    for (int mi = 0; mi < 4; mi++)
                        ac2[mi][ni] = __builtin_amdgcn_mfma_f32_16x16x32_bf16(af[mi], bf, ac2[mi][ni], 0, 0, 0);
                }
            }
            int gg2 = e*6 + 5 + grp;   // next group index
            __builtin_amdgcn_sched_barrier(0);
            __builtin_amdgcn_s_barrier();                  // WB reads done
            if (gg2 < 48){
                WGROUP_STAGE(gg2);
                asm volatile("s_waitcnt vmcnt(0)" ::: "memory");
            }
            __builtin_amdgcn_s_barrier();
            __builtin_amdgcn_sched_barrier(0);
        }
        // fused += gw[:,e] * (eo + b2)
        #pragma unroll
        for (int mi = 0; mi < 4; mi++){
            f32x4 gwv = *(const f32x4*)(lds + GWT_OFF + e*512 + (wr*64 + mi*16 + q*4)*4);
            #pragma unroll
            for (int ni = 0; ni < 4; ni++){
                int col = wc*64 + ni*16 + lr;
                float b2v = bf2f(b2L[e*128 + col]);
                #pragma unroll
                for (int j = 0; j < 4; j++)
                    fus[mi][ni][j] += gwv[j] * (ac2[mi][ni][j] + b2v);
            }
        }
    }
#undef WGROUP_STAGE

    __builtin_amdgcn_sched_barrier(0);
    __builtin_amdgcn_s_barrier();                      // all Hs(h7) reads done
    // fused -> Hs (bf16, XOR-swizzled)
    #pragma unroll
    for (int mi = 0; mi < 4; mi++)
        #pragma unroll
        for (int ni = 0; ni < 4; ni++){
            int col = wc*64 + ni*16 + lr;
            #pragma unroll
            for (int j = 0; j < 4; j++){
                int row = wr*64 + mi*16 + q*4 + j;
                *(u16*)(HsB + row*256 + ((col*2) ^ ((row & 7) << 4))) = f2bf(fus[mi][ni][j]);
            }
        }
    asm volatile("s_waitcnt lgkmcnt(0)" ::: "memory");
    __builtin_amdgcn_sched_barrier(0);
    __builtin_amdgcn_s_barrier();

    // ---- penult = relu(fused @ pre_w + pre_b): wave wid -> rows wid*32..+32 ----
    f32x4 ap[2][4];
    #pragma unroll
    for (int i = 0; i < 2; i++)
        #pragma unroll
        for (int j = 0; j < 4; j++) ap[i][j] = {0.f, 0.f, 0.f, 0.f};
    #pragma unroll
    for (int kt = 0; kt < 4; kt++){
        int cb = kt*64 + q*16;
        #pragma unroll
        for (int mi = 0; mi < 2; mi++){
            int row = wid*32 + mi*16 + lr;
            bf16x8 af = *(const bf16x8*)(HsB + row*256 + (cb ^ ((row & 7) << 4)));
            #pragma unroll
            for (int ni = 0; ni < 4; ni++){
                bf16x8 bf = *(const bf16x8*)(prwT + (size_t)(ni*16 + lr)*128 + kt*32 + q*8);
                ap[mi][ni] = __builtin_amdgcn_mfma_f32_16x16x32_bf16(af, bf, ap[mi][ni], 0, 0, 0);
            }
        }
    }
    float* Pen = (float*)lds;   // [128][68], Xs region dead
    #pragma unroll
    for (int mi = 0; mi < 2; mi++)
        #pragma unroll
        for (int ni = 0; ni < 4; ni++){
            int col = ni*16 + lr;
            float pbv = pre_b[col];
            #pragma unroll
            for (int j = 0; j < 4; j++){
                int row = wid*32 + mi*16 + q*4 + j;
                Pen[row*68 + col] = fmaxf(ap[mi][ni][j] + pbv, 0.f);
            }
        }
    asm volatile("s_waitcnt lgkmcnt(0)" ::: "memory");
    __builtin_amdgcn_sched_barrier(0);
    __builtin_amdgcn_s_barrier();
    // ---- head ----
    {
        int r = tid >> 1, c = tid & 1;
        float s = head_b[c];
        #pragma unroll 8
        for (int k = 0; k < 64; k++) s += Pen[r*68 + k] * head_w[k*2 + c];
        out[(size_t)(blk*128 + r)*2 + c] = s;
    }
}

extern "C" void kernel_launch(void* const* d_in, const int* in_sizes, int n_in,
                              void* d_out, int out_size, void* d_ws, size_t ws_size,
                              hipStream_t stream) {
    const float* ft     = (const float*)d_in[0];
    const float* fa     = (const float*)d_in[1];
    const float* fv     = (const float*)d_in[2];
    const float* proj_w = (const float*)d_in[3];
    const float* proj_b = (const float*)d_in[4];
    const float* exp_w1 = (const float*)d_in[5];
    const float* exp_b1 = (const float*)d_in[6];
    const float* exp_w2 = (const float*)d_in[7];
    const float* exp_b2 = (const float*)d_in[8];
    const float* gate_w = (const float*)d_in[9];
    const float* gate_b = (const float*)d_in[10];
    const float* pre_w  = (const float*)d_in[11];
    const float* pre_b  = (const float*)d_in[12];
    const float* head_w = (const float*)d_in[13];
    const float* head_b = (const float*)d_in[14];
    float* out = (float*)d_out;

    u16* pimg  = (u16*)d_ws;                      // 294912
    u16* w1img = pimg + 294912;                   // 393216
    u16* w2img = w1img + 393216;                  // 131072
    u16* prwT  = w2img + 131072;                  // 8192
    u16* gwimg = prwT + 8192;                     // 6144

    cast_weights_kernel<<<3256, 256, 0, stream>>>(proj_w, exp_w1, exp_w2, pre_w, gate_w,
                                                  pimg, w1img, w2img, prwT, gwimg);
    fused_kernel<<<256, 256, 0, stream>>>(ft, fa, fv, pimg, proj_b,
                                          w1img, w2img, prwT, gwimg,
                                          gate_b, exp_b1, exp_b2,
                                          pre_b, head_w, head_b, out);
}

// Round 15
// 116.892 us; speedup vs baseline: 1.1656x; 1.1656x over previous
//
#include <hip/hip_runtime.h>
#include <hip/hip_bf16.h>

#define B_ROWS 32768

typedef unsigned short u16;
typedef unsigned int u32;
typedef float f32x4 __attribute__((ext_vector_type(4)));
typedef __bf16 bf16x8 __attribute__((ext_vector_type(8)));

__device__ __forceinline__ u16 f2bf(float f){
    union { float f; u32 u; } v; v.f = f;
    return (u16)((v.u + 0x7FFFu + ((v.u >> 16) & 1u)) >> 16);
}
__device__ __forceinline__ float bf2f(u16 h){
    union { u32 u; float f; } v; v.u = ((u32)h) << 16; return v.f;
}
__device__ __forceinline__ u32 cvtpk(float lo, float hi){
    u32 r;
    asm("v_cvt_pk_bf16_f32 %0, %1, %2" : "=v"(r) : "v"(lo), "v"(hi));
    return r;
}
__device__ __forceinline__ void async_cp16(void* lds_dst, const void* g_src){
    __builtin_amdgcn_global_load_lds(
        (const __attribute__((address_space(1))) unsigned int*)g_src,
        (__attribute__((address_space(3))) unsigned int*)lds_dst, 16, 0, 0);
}

// ---------------- weight cast/transpose into staging-friendly images ----------
// pimg : [3][24][4096 u16]  XOR-swizzled proj-B LDS chunk image (BK=32)
// w1img: [8][12 chunks][q:4][col:128][8]
// w2img: [8][4 chunks][q:4][col:128][8]
// prwT : [64][128] plain [o][k]
// gwimg: [16][384] zero-padded gate weights, [e][k]
__global__ void cast_weights_kernel(const float* __restrict__ proj_w,
                                    const float* __restrict__ exp_w1,
                                    const float* __restrict__ exp_w2,
                                    const float* __restrict__ pre_w,
                                    const float* __restrict__ gate_w,
                                    u16* __restrict__ pimg, u16* __restrict__ w1img,
                                    u16* __restrict__ w2img, u16* __restrict__ prwT,
                                    u16* __restrict__ gwimg){
    int i = blockIdx.x * 256 + threadIdx.x;
    if (i < 294912){                       // pimg (BK=32 chunks)
        int m = i / 98304, r = i % 98304;
        int c = r / 4096, rr = r % 4096;
        int col = rr >> 5, kk = rr & 31;
        int kb = kk ^ (((col >> 1) & 3) << 3);
        pimg[i] = f2bf(proj_w[m*98304 + (c*32 + kb)*128 + col]);
    } else if (i < 688128){                // w1img
        int j = i - 294912;
        int e = j / 49152, r = j % 49152;
        int ph = r / 4096, rr = r % 4096;
        int q = rr >> 10, col = (rr >> 3) & 127, el = rr & 7;
        w1img[j] = f2bf(exp_w1[e*49152 + (ph*32 + q*8 + el)*128 + col]);
    } else if (i < 819200){                // w2img
        int j = i - 688128;
        int e = j / 16384, r = j % 16384;
        int c2 = r / 4096, rr = r % 4096;
        int q = rr >> 10, col = (rr >> 3) & 127, el = rr & 7;
        w2img[j] = f2bf(exp_w2[e*16384 + (c2*32 + q*8 + el)*128 + col]);
    } else if (i < 827392){                // prwT
        int j = i - 819200;
        int o = j / 128, k = j % 128;
        prwT[j] = f2bf(pre_w[k*64 + o]);
    } else if (i < 833536){                // gwimg
        int j = i - 827392;
        int e = j / 384, k = j % 384;
        gwimg[j] = (e < 8) ? f2bf(gate_w[k*8 + e]) : (u16)0;
    }
}

// ---------------- fully fused: proj + gate + experts + pre + head -------------
// 256 blocks x 512 threads (8 waves 4x2), 128 rows/block, 1 block/CU, 160KB LDS.
// Phase A: depth-2 pipeline (r10) — A 3-slot ring, B 2-slot, steady vmcnt(5).
// Phase C: grouped (r13, 48 barrier-pairs) + X-IN-REGISTERS: each wave preloads
//   its 12x2 x-fragments (96 VGPR) once; w1 chunks read only B from LDS.
#define XS_OFF   0          // 96 KB  x image [half2][kt12][q4][row64][16B]
#define A_OFF    98304      // 3 x 16 KB A-feat ring (phase A)
#define B_OFF    147456     // 2 x 8 KB pimg ring (phase A)
#define HS_OFF   98304      // phase C: 128 x 256B XOR-swizzled = 32768
#define GWT_OFF  131072     // f32 [8][128] = 4096
#define B1_OFF   135168     // bf16 [8][128] = 2048
#define B2_OFF   137216     // bf16 [8][128] = 2048
#define WB_OFF   139264     // 3 x 8 KB expert group buffer -> 163840

__global__ __launch_bounds__(512, 1) void fused_kernel(
    const float* __restrict__ ft, const float* __restrict__ fa, const float* __restrict__ fv,
    const u16* __restrict__ pimg, const float* __restrict__ proj_b,
    const u16* __restrict__ w1img, const u16* __restrict__ w2img,
    const u16* __restrict__ prwT, const u16* __restrict__ gwimg,
    const float* __restrict__ gate_b, const float* __restrict__ exp_b1, const float* __restrict__ exp_b2,
    const float* __restrict__ pre_b, const float* __restrict__ head_w, const float* __restrict__ head_b,
    float* __restrict__ out)
{
    __shared__ __align__(16) char lds[163840];
    const int tid = threadIdx.x;
    const int lane = tid & 63, wid = tid >> 6;   // 8 waves
    const int wr = wid >> 1, wc = wid & 1;       // 4 x 2
    const int lr = lane & 15, q = lane >> 4;
    const int blk = blockIdx.x;
    const int row0 = blk * 128;
    const char* w1b = (const char*)w1img;
    const char* w2b = (const char*)w2img;
    char* HsB = lds + HS_OFF;
    u16* b1L = (u16*)(lds + B1_OFF);
    u16* b2L = (u16*)(lds + B2_OFF);

    // ---- prologue: proj_b -> registers, drain so pipeline counts are exact ----
    float pb0[4], pb1[4], pb2[4];
    #pragma unroll
    for (int ni = 0; ni < 4; ni++){
        int c = wc*64 + ni*16 + lr;
        pb0[ni] = proj_b[c];
        pb1[ni] = proj_b[128 + c];
        pb2[ni] = proj_b[256 + c];
    }
    asm volatile("s_waitcnt vmcnt(0)" ::: "memory");

    // A staging source offsets (XOR-pre-swizzled global addresses, linear LDS dst)
    u32 aoffs[2];
    #pragma unroll
    for (int i = 0; i < 2; i++){
        int P = i*8192 + tid*16;
        int row = P >> 7, inner = P & 127;
        aoffs[i] = (u32)((row0 + row)*3072 + (inner ^ ((row & 7) << 4)));
    }

#define ASTAGE(c) do{                                                          \
        int mm_ = (c) / 24, kk_ = (c) % 24;                                    \
        const char* ab_ = (const char*)(mm_ == 0 ? ft : mm_ == 1 ? fa : fv);   \
        char* la_ = lds + A_OFF + ((c) % 3)*16384 + tid*16;                    \
        async_cp16(la_,        ab_ + aoffs[0] + kk_*128);                      \
        async_cp16(la_ + 8192, ab_ + aoffs[1] + kk_*128);                      \
    }while(0)

#define BSTAGE(c) do{                                                          \
        int mm_ = (c) / 24, kk_ = (c) % 24;                                    \
        async_cp16(lds + B_OFF + ((c) % 2)*8192 + tid*16,                      \
                   (const char*)pimg + mm_*196608 + kk_*8192 + tid*16);        \
    }while(0)

#define PCONSUME(c) do{                                                        \
        const char* Abuf = lds + A_OFF + ((c) % 3)*16384;                      \
        const char* Bbuf = lds + B_OFF + ((c) % 2)*8192;                       \
        bf16x8 af[2];                                                          \
        _Pragma("unroll")                                                      \
        for (int mi = 0; mi < 2; mi++){                                        \
            int row = wr*32 + mi*16 + lr;                                      \
            int aoff = row*128 + ((q*32) ^ ((row & 7) << 4));                  \
            f32x4 a0 = *(const f32x4*)(Abuf + aoff);                           \
            f32x4 a1 = *(const f32x4*)(Abuf + (aoff ^ 16));                    \
            union { u32 w[4]; bf16x8 v; } u;                                   \
            u.w[0] = cvtpk(a0.x, a0.y); u.w[1] = cvtpk(a0.z, a0.w);            \
            u.w[2] = cvtpk(a1.x, a1.y); u.w[3] = cvtpk(a1.z, a1.w);            \
            af[mi] = u.v;                                                      \
        }                                                                      \
        __builtin_amdgcn_s_setprio(1);                                         \
        _Pragma("unroll")                                                      \
        for (int ni = 0; ni < 4; ni++){                                        \
            int col = wc*64 + ni*16 + lr;                                      \
            int boff = col*64 + ((q*16) ^ (((col >> 1) & 3) << 4));            \
            bf16x8 bf = *(const bf16x8*)(Bbuf + boff);                         \
            acc[0][ni] = __builtin_amdgcn_mfma_f32_16x16x32_bf16(af[0], bf, acc[0][ni], 0, 0, 0); \
            acc[1][ni] = __builtin_amdgcn_mfma_f32_16x16x32_bf16(af[1], bf, acc[1][ni], 0, 0, 0); \
        }                                                                      \
        __builtin_amdgcn_s_setprio(0);                                         \
    }while(0)

// one modality: 24 chunk iterations + epilogue into Xs image (MC is a literal)
#define PHASE_A_MOD(MC, PB) do{                                                \
        _Pragma("unroll 1")                                                    \
        for (int kt = 0; kt < 24; kt++){                                       \
            int t = MC*24 + kt;                                                \
            __builtin_amdgcn_sched_barrier(0);                                 \
            __builtin_amdgcn_s_barrier();                                      \
            if (t < 71) BSTAGE(t + 1);                                         \
            if (t < 70) ASTAGE(t + 2);                                         \
            if (t < 70)       asm volatile("s_waitcnt vmcnt(5)" ::: "memory"); \
            else if (t == 70) asm volatile("s_waitcnt vmcnt(3)" ::: "memory"); \
            else              asm volatile("s_waitcnt vmcnt(0)" ::: "memory"); \
            __builtin_amdgcn_s_barrier();                                      \
            __builtin_amdgcn_sched_barrier(0);                                 \
            PCONSUME(t);                                                       \
        }                                                                      \
        _Pragma("unroll")                                                      \
        for (int mi = 0; mi < 2; mi++)                                         \
            _Pragma("unroll")                                                  \
            for (int ni = 0; ni < 4; ni++){                                    \
                int lcol = wc*64 + ni*16 + lr;                                 \
                int colg = MC*128 + lcol;                                      \
                int ktI = colg >> 5, qI = (colg >> 3) & 3, el = colg & 7;      \
                _Pragma("unroll")                                              \
                for (int j = 0; j < 4; j++){                                   \
                    int row = wr*32 + mi*16 + q*4 + j;                         \
                    *(u16*)(lds + (row >> 6)*49152 + ktI*4096 + qI*1024        \
                            + (row & 63)*16 + el*2) = f2bf(acc[mi][ni][j] + PB[ni]); \
                    acc[mi][ni][j] = 0.f;                                      \
                }                                                              \
            }                                                                  \
    }while(0)

    f32x4 acc[2][4];
    #pragma unroll
    for (int i = 0; i < 2; i++)
        #pragma unroll
        for (int j = 0; j < 4; j++) acc[i][j] = {0.f, 0.f, 0.f, 0.f};

    BSTAGE(0); ASTAGE(0); ASTAGE(1);
    PHASE_A_MOD(0, pb0);
    PHASE_A_MOD(1, pb1);
    PHASE_A_MOD(2, pb2);
#undef ASTAGE
#undef BSTAGE
#undef PCONSUME
#undef PHASE_A_MOD

    asm volatile("s_waitcnt lgkmcnt(0)" ::: "memory");
    __builtin_amdgcn_sched_barrier(0);
    __builtin_amdgcn_s_barrier();                          // Xs image complete

    // ---- x fragments -> registers (96 VGPR): read ONCE, reused by all 8 experts
    bf16x8 xreg[12][2];
    {
        const char* xa0 = lds + (wr >> 1)*49152 + q*1024;
        #pragma unroll
        for (int ph = 0; ph < 12; ph++){
            xreg[ph][0] = *(const bf16x8*)(xa0 + ph*4096 + ((wr & 1)*32 + lr)*16);
            xreg[ph][1] = *(const bf16x8*)(xa0 + ph*4096 + ((wr & 1)*32 + 16 + lr)*16);
        }
    }

    // ---- phase B: group 0 (chunks 0,1,2) prefetch; bias stage; gate ----
    {
        const char* src = w1b + tid*16;
        async_cp16(lds + WB_OFF + 0*8192 + tid*16, src);
        async_cp16(lds + WB_OFF + 1*8192 + tid*16, src + 8192);
        async_cp16(lds + WB_OFF + 2*8192 + tid*16, src + 16384);
    }
    for (int i = tid; i < 1024; i += 512){
        b1L[i] = f2bf(exp_b1[i]);
        b2L[i] = f2bf(exp_b2[i]);
    }
    {
        f32x4 ga = {0.f, 0.f, 0.f, 0.f};
        const char* xb = lds + (wid >> 2)*49152 + ((wid & 3)*16 + lr)*16 + q*1024;
        const u16* gwp = gwimg + lr*384 + q*8;
        #pragma unroll
        for (int kt = 0; kt < 12; kt++){
            bf16x8 af = *(const bf16x8*)(xb + kt*4096);
            bf16x8 gb = *(const bf16x8*)(gwp + kt*32);
            ga = __builtin_amdgcn_mfma_f32_16x16x32_bf16(af, gb, ga, 0, 0, 0);
        }
        float gbv = gate_b[lr & 7];
        float gw4[4];
        #pragma unroll
        for (int j = 0; j < 4; j++){
            float v = ga[j] + gbv;
            float mx = v;
            mx = fmaxf(mx, __shfl_xor(mx, 1));
            mx = fmaxf(mx, __shfl_xor(mx, 2));
            mx = fmaxf(mx, __shfl_xor(mx, 4));
            float s = __expf(v - mx);
            float t = s;
            t += __shfl_xor(t, 1);
            t += __shfl_xor(t, 2);
            t += __shfl_xor(t, 4);
            gw4[j] = s / t;
        }
        if (lr < 8){
            f32x4 wv = {gw4[0], gw4[1], gw4[2], gw4[3]};
            *(f32x4*)(lds + GWT_OFF + lr*512 + (wid*16 + q*4)*4) = wv;
        }
    }
    asm volatile("s_waitcnt vmcnt(0) lgkmcnt(0)" ::: "memory");   // group0+biases+GWT landed
    __builtin_amdgcn_sched_barrier(0);
    __builtin_amdgcn_s_barrier();

    // ---- phase C: 48 groups (per expert: 4x3 w1-chunks + 2x2 w2-chunks) ----
#define WGROUP_STAGE(gg2) do{                                                  \
        int e2_ = (gg2) / 6, i2_ = (gg2) % 6;                                  \
        if (i2_ < 4){                                                          \
            const char* src_ = w1b + e2_*98304 + i2_*3*8192 + tid*16;          \
            async_cp16(lds + WB_OFF + 0*8192 + tid*16, src_);                  \
            async_cp16(lds + WB_OFF + 1*8192 + tid*16, src_ + 8192);           \
            async_cp16(lds + WB_OFF + 2*8192 + tid*16, src_ + 16384);          \
        } else {                                                               \
            const char* src_ = w2b + e2_*32768 + (i2_ - 4)*2*8192 + tid*16;    \
            async_cp16(lds + WB_OFF + 0*8192 + tid*16, src_);                  \
            async_cp16(lds + WB_OFF + 1*8192 + tid*16, src_ + 8192);           \
        }                                                                      \
    }while(0)

    f32x4 fus[2][4];
    #pragma unroll
    for (int i = 0; i < 2; i++)
        #pragma unroll
        for (int j = 0; j < 4; j++) fus[i][j] = {0.f, 0.f, 0.f, 0.f};

    #pragma unroll 1
    for (int e = 0; e < 8; e++){
        f32x4 ac1[2][4];
        #pragma unroll
        for (int i = 0; i < 2; i++)
            #pragma unroll
            for (int j = 0; j < 4; j++) ac1[i][j] = {0.f, 0.f, 0.f, 0.f};

        #pragma unroll                                     // FULL unroll: xreg[ph] static
        for (int grp = 0; grp < 4; grp++){
            __builtin_amdgcn_s_setprio(1);
            #pragma unroll
            for (int c = 0; c < 3; c++){
                int ph = grp*3 + c;
                const char* wsl = lds + WB_OFF + c*8192 + q*2048;
                #pragma unroll
                for (int ni = 0; ni < 4; ni++){
                    bf16x8 bf = *(const bf16x8*)(wsl + (wc*64 + ni*16 + lr)*16);
                    ac1[0][ni] = __builtin_amdgcn_mfma_f32_16x16x32_bf16(xreg[ph][0], bf, ac1[0][ni], 0, 0, 0);
                    ac1[1][ni] = __builtin_amdgcn_mfma_f32_16x16x32_bf16(xreg[ph][1], bf, ac1[1][ni], 0, 0, 0);
                }
            }
            __builtin_amdgcn_s_setprio(0);
            if (grp == 3){
                // h = relu(ac1 + b1) -> Hs (XOR-swizzled)
                #pragma unroll
                for (int mi = 0; mi < 2; mi++)
                    #pragma unroll
                    for (int ni = 0; ni < 4; ni++){
                        int col = wc*64 + ni*16 + lr;
                        float b1v = bf2f(b1L[e*128 + col]);
                        #pragma unroll
                        for (int j = 0; j < 4; j++){
                            int row = wr*32 + mi*16 + q*4 + j;
                            *(u16*)(HsB + row*256 + ((col*2) ^ ((row & 7) << 4)))
                                = f2bf(fmaxf(ac1[mi][ni][j] + b1v, 0.f));
                        }
                    }
                asm volatile("s_waitcnt lgkmcnt(0)" ::: "memory");
            }
            __builtin_amdgcn_sched_barrier(0);
            __builtin_amdgcn_s_barrier();                  // WB reads (and Hs writes) done
            WGROUP_STAGE(e*6 + grp + 1);
            asm volatile("s_waitcnt vmcnt(0)" ::: "memory");
            __builtin_amdgcn_s_barrier();                  // next group + Hs visible
            __builtin_amdgcn_sched_barrier(0);
        }

        f32x4 ac2[2][4];
        #pragma unroll
        for (int i = 0; i < 2; i++)
            #pragma unroll
            for (int j = 0; j < 4; j++) ac2[i][j] = {0.f, 0.f, 0.f, 0.f};

        #pragma unroll 1
        for (int grp = 0; grp < 2; grp++){
            #pragma unroll
            for (int c = 0; c < 2; c++){
                int p2 = grp*2 + c;
                const char* wsl = lds + WB_OFF + c*8192 + q*2048;
                int cb = p2*64 + q*16;
                int rowA = wr*32 + lr;
                int rowB = wr*32 + 16 + lr;
                bf16x8 af0 = *(const bf16x8*)(HsB + rowA*256 + (cb ^ ((rowA & 7) << 4)));
                bf16x8 af1 = *(const bf16x8*)(HsB + rowB*256 + (cb ^ ((rowB & 7) << 4)));
                __builtin_amdgcn_s_setprio(1);
                #pragma unroll
                for (int ni = 0; ni < 4; ni++){
                    bf16x8 bf = *(const bf16x8*)(wsl + (wc*64 + ni*16 + lr)*16);
                    ac2[0][ni] = __builtin_amdgcn_mfma_f32_16x16x32_bf16(af0, bf, ac2[0][ni], 0, 0, 0);
                    ac2[1][ni] = __builtin_amdgcn_mfma_f32_16x16x32_bf16(af1, bf, ac2[1][ni], 0, 0, 0);
                }
                __builtin_amdgcn_s_setprio(0);
            }
            int gg2 = e*6 + 5 + grp;   // next group index
            __builtin_amdgcn_sched_barrier(0);
            __builtin_amdgcn_s_barrier();                  // WB reads done
            if (gg2 < 48){
                WGROUP_STAGE(gg2);
                asm volatile("s_waitcnt vmcnt(0)" ::: "memory");
            }
            __builtin_amdgcn_s_barrier();
            __builtin_amdgcn_sched_barrier(0);
        }
        // fused += gw[:,e] * (eo + b2)
        #pragma unroll
        for (int mi = 0; mi < 2; mi++){
            f32x4 gwv = *(const f32x4*)(lds + GWT_OFF + e*512 + (wr*32 + mi*16 + q*4)*4);
            #pragma unroll
            for (int ni = 0; ni < 4; ni++){
                int col = wc*64 + ni*16 + lr;
                float b2v = bf2f(b2L[e*128 + col]);
                #pragma unroll
                for (int j = 0; j < 4; j++)
                    fus[mi][ni][j] += gwv[j] * (ac2[mi][ni][j] + b2v);
            }
        }
    }
#undef WGROUP_STAGE

    __builtin_amdgcn_sched_barrier(0);
    __builtin_amdgcn_s_barrier();                      // all Hs(h7) reads done
    // fused -> Hs (bf16, XOR-swizzled)
    #pragma unroll
    for (int mi = 0; mi < 2; mi++)
        #pragma unroll
        for (int ni = 0; ni < 4; ni++){
            int col = wc*64 + ni*16 + lr;
            #pragma unroll
            for (int j = 0; j < 4; j++){
                int row = wr*32 + mi*16 + q*4 + j;
                *(u16*)(HsB + row*256 + ((col*2) ^ ((row & 7) << 4))) = f2bf(fus[mi][ni][j]);
            }
        }
    asm volatile("s_waitcnt lgkmcnt(0)" ::: "memory");
    __builtin_amdgcn_sched_barrier(0);
    __builtin_amdgcn_s_barrier();

    // ---- penult = relu(fused @ pre_w + pre_b): wave wid -> rows wid*16..+16 ----
    f32x4 ap[4];
    #pragma unroll
    for (int i = 0; i < 4; i++) ap[i] = {0.f, 0.f, 0.f, 0.f};
    #pragma unroll
    for (int kt = 0; kt < 4; kt++){
        int row = wid*16 + lr;
        int cb = kt*64 + q*16;
        bf16x8 af = *(const bf16x8*)(HsB + row*256 + (cb ^ ((row & 7) << 4)));
        #pragma unroll
        for (int ni = 0; ni < 4; ni++){
            bf16x8 bf = *(const bf16x8*)(prwT + (size_t)(ni*16 + lr)*128 + kt*32 + q*8);
            ap[ni] = __builtin_amdgcn_mfma_f32_16x16x32_bf16(af, bf, ap[ni], 0, 0, 0);
        }
    }
    float* Pen = (float*)lds;   // [128][68], Xs region dead
    #pragma unroll
    for (int ni = 0; ni < 4; ni++){
        int col = ni*16 + lr;
        float pbv = pre_b[col];
        #pragma unroll
        for (int j = 0; j < 4; j++){
            int row = wid*16 + q*4 + j;
            Pen[row*68 + col] = fmaxf(ap[ni][j] + pbv, 0.f);
        }
    }
    asm volatile("s_waitcnt lgkmcnt(0)" ::: "memory");
    __builtin_amdgcn_sched_barrier(0);
    __builtin_amdgcn_s_barrier();
    // ---- head ----
    if (tid < 256){
        int r = tid >> 1, c = tid & 1;
        float s = head_b[c];
        #pragma unroll 8
        for (int k = 0; k < 64; k++) s += Pen[r*68 + k] * head_w[k*2 + c];
        out[(size_t)(blk*128 + r)*2 + c] = s;
    }
}

extern "C" void kernel_launch(void* const* d_in, const int* in_sizes, int n_in,
                              void* d_out, int out_size, void* d_ws, size_t ws_size,
                              hipStream_t stream) {
    const float* ft     = (const float*)d_in[0];
    const float* fa     = (const float*)d_in[1];
    const float* fv     = (const float*)d_in[2];
    const float* proj_w = (const float*)d_in[3];
    const float* proj_b = (const float*)d_in[4];
    const float* exp_w1 = (const float*)d_in[5];
    const float* exp_b1 = (const float*)d_in[6];
    const float* exp_w2 = (const float*)d_in[7];
    const float* exp_b2 = (const float*)d_in[8];
    const float* gate_w = (const float*)d_in[9];
    const float* gate_b = (const float*)d_in[10];
    const float* pre_w  = (const float*)d_in[11];
    const float* pre_b  = (const float*)d_in[12];
    const float* head_w = (const float*)d_in[13];
    const float* head_b = (const float*)d_in[14];
    float* out = (float*)d_out;

    u16* pimg  = (u16*)d_ws;                      // 294912
    u16* w1img = pimg + 294912;                   // 393216
    u16* w2img = w1img + 393216;                  // 131072
    u16* prwT  = w2img + 131072;                  // 8192
    u16* gwimg = prwT + 8192;                     // 6144

    cast_weights_kernel<<<3256, 256, 0, stream>>>(proj_w, exp_w1, exp_w2, pre_w, gate_w,
                                                  pimg, w1img, w2img, prwT, gwimg);
    fused_kernel<<<256, 512, 0, stream>>>(ft, fa, fv, pimg, proj_b,
                                          w1img, w2img, prwT, gwimg,
                                          gate_b, exp_b1, exp_b2,
                                          pre_b, head_w, head_b, out);
}

// Round 16
// 104.152 us; speedup vs baseline: 1.3082x; 1.1223x over previous
//
#include <hip/hip_runtime.h>
#include <hip/hip_bf16.h>

#define B_ROWS 32768

typedef unsigned short u16;
typedef unsigned int u32;
typedef float f32x4 __attribute__((ext_vector_type(4)));
typedef __bf16 bf16x8 __attribute__((ext_vector_type(8)));

__device__ __forceinline__ u16 f2bf(float f){
    union { float f; u32 u; } v; v.f = f;
    return (u16)((v.u + 0x7FFFu + ((v.u >> 16) & 1u)) >> 16);
}
__device__ __forceinline__ float bf2f(u16 h){
    union { u32 u; float f; } v; v.u = ((u32)h) << 16; return v.f;
}
__device__ __forceinline__ u32 cvtpk(float lo, float hi){
    u32 r;
    asm("v_cvt_pk_bf16_f32 %0, %1, %2" : "=v"(r) : "v"(lo), "v"(hi));
    return r;
}
__device__ __forceinline__ void async_cp16(void* lds_dst, const void* g_src){
    __builtin_amdgcn_global_load_lds(
        (const __attribute__((address_space(1))) unsigned int*)g_src,
        (__attribute__((address_space(3))) unsigned int*)lds_dst, 16, 0, 0);
}

// ---------------- weight cast/transpose into staging-friendly images ----------
// pimg : [3][24][4096 u16]  XOR-swizzled proj-B LDS chunk image (BK=32)
// w1img: [8][12 chunks][q:4][col:128][8]
// w2img: [8][4 chunks][q:4][col:128][8]
// prwT : [64][128] plain [o][k]
// gwimg: [16][384] zero-padded gate weights, [e][k]
__global__ void cast_weights_kernel(const float* __restrict__ proj_w,
                                    const float* __restrict__ exp_w1,
                                    const float* __restrict__ exp_w2,
                                    const float* __restrict__ pre_w,
                                    const float* __restrict__ gate_w,
                                    u16* __restrict__ pimg, u16* __restrict__ w1img,
                                    u16* __restrict__ w2img, u16* __restrict__ prwT,
                                    u16* __restrict__ gwimg){
    int i = blockIdx.x * 256 + threadIdx.x;
    if (i < 294912){                       // pimg (BK=32 chunks)
        int m = i / 98304, r = i % 98304;
        int c = r / 4096, rr = r % 4096;
        int col = rr >> 5, kk = rr & 31;
        int kb = kk ^ (((col >> 1) & 3) << 3);
        pimg[i] = f2bf(proj_w[m*98304 + (c*32 + kb)*128 + col]);
    } else if (i < 688128){                // w1img
        int j = i - 294912;
        int e = j / 49152, r = j % 49152;
        int ph = r / 4096, rr = r % 4096;
        int q = rr >> 10, col = (rr >> 3) & 127, el = rr & 7;
        w1img[j] = f2bf(exp_w1[e*49152 + (ph*32 + q*8 + el)*128 + col]);
    } else if (i < 819200){                // w2img
        int j = i - 688128;
        int e = j / 16384, r = j % 16384;
        int c2 = r / 4096, rr = r % 4096;
        int q = rr >> 10, col = (rr >> 3) & 127, el = rr & 7;
        w2img[j] = f2bf(exp_w2[e*16384 + (c2*32 + q*8 + el)*128 + col]);
    } else if (i < 827392){                // prwT
        int j = i - 819200;
        int o = j / 128, k = j % 128;
        prwT[j] = f2bf(pre_w[k*64 + o]);
    } else if (i < 833536){                // gwimg
        int j = i - 827392;
        int e = j / 384, k = j % 384;
        gwimg[j] = (e < 8) ? f2bf(gate_w[k*8 + e]) : (u16)0;
    }
}

// ---------------- fully fused: proj + gate + experts + pre + head -------------
// 256 blocks x 512 threads (8 waves 4x2), 128 rows/block, 1 block/CU, 160KB LDS.
// Phase A: depth-2 pipeline (r10) — A 3-slot ring, B 2-slot, steady vmcnt(5).
// Phase C: x-in-registers (r15) + NEW 2x24KB double-buffered group ring in the
//   dead Xs region, counted vmcnt(3) — no drains in the main loop.
#define A_OFF    98304      // phase A: 3 x 16 KB A-feat ring
#define B_OFF    147456     // phase A: 2 x 8 KB pimg ring -> 163840
// phase C overlay (Xs region is dead after xreg preload + gate):
#define HS2      0          // 128 x 256B XOR-swizzled = 32768
#define GWT2     32768      // f32 [8][128] = 4096
#define B1_2     36864      // bf16 [8][128] = 2048
#define B2_2     38912      // bf16 [8][128] = 2048
#define WB2      40960      // 2 x 24576 group ring -> 90112

__global__ __launch_bounds__(512, 1) void fused_kernel(
    const float* __restrict__ ft, const float* __restrict__ fa, const float* __restrict__ fv,
    const u16* __restrict__ pimg, const float* __restrict__ proj_b,
    const u16* __restrict__ w1img, const u16* __restrict__ w2img,
    const u16* __restrict__ prwT, const u16* __restrict__ gwimg,
    const float* __restrict__ gate_b, const float* __restrict__ exp_b1, const float* __restrict__ exp_b2,
    const float* __restrict__ pre_b, const float* __restrict__ head_w, const float* __restrict__ head_b,
    float* __restrict__ out)
{
    __shared__ __align__(16) char lds[163840];
    const int tid = threadIdx.x;
    const int lane = tid & 63, wid = tid >> 6;   // 8 waves
    const int wr = wid >> 1, wc = wid & 1;       // 4 x 2
    const int lr = lane & 15, q = lane >> 4;
    const int blk = blockIdx.x;
    const int row0 = blk * 128;
    const char* w1b = (const char*)w1img;
    const char* w2b = (const char*)w2img;
    char* HsB = lds + HS2;
    u16* b1L = (u16*)(lds + B1_2);
    u16* b2L = (u16*)(lds + B2_2);

    // ---- prologue: proj_b -> registers, drain so pipeline counts are exact ----
    float pb0[4], pb1[4], pb2[4];
    #pragma unroll
    for (int ni = 0; ni < 4; ni++){
        int c = wc*64 + ni*16 + lr;
        pb0[ni] = proj_b[c];
        pb1[ni] = proj_b[128 + c];
        pb2[ni] = proj_b[256 + c];
    }
    asm volatile("s_waitcnt vmcnt(0)" ::: "memory");

    // A staging source offsets (XOR-pre-swizzled global addresses, linear LDS dst)
    u32 aoffs[2];
    #pragma unroll
    for (int i = 0; i < 2; i++){
        int P = i*8192 + tid*16;
        int row = P >> 7, inner = P & 127;
        aoffs[i] = (u32)((row0 + row)*3072 + (inner ^ ((row & 7) << 4)));
    }

#define ASTAGE(c) do{                                                          \
        int mm_ = (c) / 24, kk_ = (c) % 24;                                    \
        const char* ab_ = (const char*)(mm_ == 0 ? ft : mm_ == 1 ? fa : fv);   \
        char* la_ = lds + A_OFF + ((c) % 3)*16384 + tid*16;                    \
        async_cp16(la_,        ab_ + aoffs[0] + kk_*128);                      \
        async_cp16(la_ + 8192, ab_ + aoffs[1] + kk_*128);                      \
    }while(0)

#define BSTAGE(c) do{                                                          \
        int mm_ = (c) / 24, kk_ = (c) % 24;                                    \
        async_cp16(lds + B_OFF + ((c) % 2)*8192 + tid*16,                      \
                   (const char*)pimg + mm_*196608 + kk_*8192 + tid*16);        \
    }while(0)

#define PCONSUME(c) do{                                                        \
        const char* Abuf = lds + A_OFF + ((c) % 3)*16384;                      \
        const char* Bbuf = lds + B_OFF + ((c) % 2)*8192;                       \
        bf16x8 af[2];                                                          \
        _Pragma("unroll")                                                      \
        for (int mi = 0; mi < 2; mi++){                                        \
            int row = wr*32 + mi*16 + lr;                                      \
            int aoff = row*128 + ((q*32) ^ ((row & 7) << 4));                  \
            f32x4 a0 = *(const f32x4*)(Abuf + aoff);                           \
            f32x4 a1 = *(const f32x4*)(Abuf + (aoff ^ 16));                    \
            union { u32 w[4]; bf16x8 v; } u;                                   \
            u.w[0] = cvtpk(a0.x, a0.y); u.w[1] = cvtpk(a0.z, a0.w);            \
            u.w[2] = cvtpk(a1.x, a1.y); u.w[3] = cvtpk(a1.z, a1.w);            \
            af[mi] = u.v;                                                      \
        }                                                                      \
        __builtin_amdgcn_s_setprio(1);                                         \
        _Pragma("unroll")                                                      \
        for (int ni = 0; ni < 4; ni++){                                        \
            int col = wc*64 + ni*16 + lr;                                      \
            int boff = col*64 + ((q*16) ^ (((col >> 1) & 3) << 4));            \
            bf16x8 bf = *(const bf16x8*)(Bbuf + boff);                         \
            acc[0][ni] = __builtin_amdgcn_mfma_f32_16x16x32_bf16(af[0], bf, acc[0][ni], 0, 0, 0); \
            acc[1][ni] = __builtin_amdgcn_mfma_f32_16x16x32_bf16(af[1], bf, acc[1][ni], 0, 0, 0); \
        }                                                                      \
        __builtin_amdgcn_s_setprio(0);                                         \
    }while(0)

// one modality: 24 chunk iterations + epilogue into Xs image (MC is a literal)
#define PHASE_A_MOD(MC, PB) do{                                                \
        _Pragma("unroll 1")                                                    \
        for (int kt = 0; kt < 24; kt++){                                       \
            int t = MC*24 + kt;                                                \
            __builtin_amdgcn_sched_barrier(0);                                 \
            __builtin_amdgcn_s_barrier();                                      \
            if (t < 71) BSTAGE(t + 1);                                         \
            if (t < 70) ASTAGE(t + 2);                                         \
            if (t < 70)       asm volatile("s_waitcnt vmcnt(5)" ::: "memory"); \
            else if (t == 70) asm volatile("s_waitcnt vmcnt(3)" ::: "memory"); \
            else              asm volatile("s_waitcnt vmcnt(0)" ::: "memory"); \
            __builtin_amdgcn_s_barrier();                                      \
            __builtin_amdgcn_sched_barrier(0);                                 \
            PCONSUME(t);                                                       \
        }                                                                      \
        _Pragma("unroll")                                                      \
        for (int mi = 0; mi < 2; mi++)                                         \
            _Pragma("unroll")                                                  \
            for (int ni = 0; ni < 4; ni++){                                    \
                int lcol = wc*64 + ni*16 + lr;                                 \
                int colg = MC*128 + lcol;                                      \
                int ktI = colg >> 5, qI = (colg >> 3) & 3, el = colg & 7;      \
                _Pragma("unroll")                                              \
                for (int j = 0; j < 4; j++){                                   \
                    int row = wr*32 + mi*16 + q*4 + j;                         \
                    *(u16*)(lds + (row >> 6)*49152 + ktI*4096 + qI*1024        \
                            + (row & 63)*16 + el*2) = f2bf(acc[mi][ni][j] + PB[ni]); \
                    acc[mi][ni][j] = 0.f;                                      \
                }                                                              \
            }                                                                  \
    }while(0)

    f32x4 acc[2][4];
    #pragma unroll
    for (int i = 0; i < 2; i++)
        #pragma unroll
        for (int j = 0; j < 4; j++) acc[i][j] = {0.f, 0.f, 0.f, 0.f};

    BSTAGE(0); ASTAGE(0); ASTAGE(1);
    PHASE_A_MOD(0, pb0);
    PHASE_A_MOD(1, pb1);
    PHASE_A_MOD(2, pb2);
#undef ASTAGE
#undef BSTAGE
#undef PCONSUME
#undef PHASE_A_MOD

    asm volatile("s_waitcnt lgkmcnt(0)" ::: "memory");
    __builtin_amdgcn_sched_barrier(0);
    __builtin_amdgcn_s_barrier();                          // Xs image complete

    // ---- xreg preload + gate: the ONLY readers of Xs ----
    bf16x8 xreg[12][2];
    {
        const char* xa0 = lds + (wr >> 1)*49152 + q*1024;
        #pragma unroll
        for (int ph = 0; ph < 12; ph++){
            xreg[ph][0] = *(const bf16x8*)(xa0 + ph*4096 + ((wr & 1)*32 + lr)*16);
            xreg[ph][1] = *(const bf16x8*)(xa0 + ph*4096 + ((wr & 1)*32 + 16 + lr)*16);
        }
    }
    float gw4[4];
    {
        f32x4 ga = {0.f, 0.f, 0.f, 0.f};
        const char* xb = lds + (wid >> 2)*49152 + ((wid & 3)*16 + lr)*16 + q*1024;
        const u16* gwp = gwimg + lr*384 + q*8;
        #pragma unroll
        for (int kt = 0; kt < 12; kt++){
            bf16x8 af = *(const bf16x8*)(xb + kt*4096);
            bf16x8 gb = *(const bf16x8*)(gwp + kt*32);
            ga = __builtin_amdgcn_mfma_f32_16x16x32_bf16(af, gb, ga, 0, 0, 0);
        }
        float gbv = gate_b[lr & 7];
        #pragma unroll
        for (int j = 0; j < 4; j++){
            float v = ga[j] + gbv;
            float mx = v;
            mx = fmaxf(mx, __shfl_xor(mx, 1));
            mx = fmaxf(mx, __shfl_xor(mx, 2));
            mx = fmaxf(mx, __shfl_xor(mx, 4));
            float s = __expf(v - mx);
            float t = s;
            t += __shfl_xor(t, 1);
            t += __shfl_xor(t, 2);
            t += __shfl_xor(t, 4);
            gw4[j] = s / t;
        }
    }
    asm volatile("s_waitcnt lgkmcnt(0)" ::: "memory");     // all Xs reads retired
    __builtin_amdgcn_sched_barrier(0);
    __builtin_amdgcn_s_barrier();                          // Xs region now dead

    // ---- phase-C group staging: uniform 3 async_cp16 per group ----
#define WGROUP_STAGE2(gg2, sl) do{                                             \
        int e2_ = (gg2) / 6, i2_ = (gg2) % 6;                                  \
        char* dst_ = lds + WB2 + (sl)*24576 + tid*16;                          \
        if (i2_ < 4){                                                          \
            const char* src_ = w1b + e2_*98304 + i2_*24576 + tid*16;           \
            async_cp16(dst_,         src_);                                    \
            async_cp16(dst_ + 8192,  src_ + 8192);                             \
            async_cp16(dst_ + 16384, src_ + 16384);                            \
        } else {                                                               \
            const char* src_ = w2b + e2_*32768 + (i2_ - 4)*16384 + tid*16;     \
            async_cp16(dst_,         src_);                                    \
            async_cp16(dst_ + 8192,  src_ + 8192);                             \
            async_cp16(dst_ + 16384, src_);   /* dup: uniform vmcnt */         \
        }                                                                      \
    }while(0)

    // GWT/biases + prefetch groups 0,1 into the reclaimed region
    if (lr < 8){
        f32x4 wv = {gw4[0], gw4[1], gw4[2], gw4[3]};
        *(f32x4*)(lds + GWT2 + lr*512 + (wid*16 + q*4)*4) = wv;
    }
    for (int i = tid; i < 1024; i += 512){
        b1L[i] = f2bf(exp_b1[i]);
        b2L[i] = f2bf(exp_b2[i]);
    }
    WGROUP_STAGE2(0, 0);
    WGROUP_STAGE2(1, 1);
    asm volatile("s_waitcnt vmcnt(0) lgkmcnt(0)" ::: "memory");
    __builtin_amdgcn_sched_barrier(0);
    __builtin_amdgcn_s_barrier();

    // ---- phase C: 48 groups, 2-slot ring, counted vmcnt(3) — never drains ----
    f32x4 fus[2][4];
    #pragma unroll
    for (int i = 0; i < 2; i++)
        #pragma unroll
        for (int j = 0; j < 4; j++) fus[i][j] = {0.f, 0.f, 0.f, 0.f};

    #pragma unroll 1
    for (int e = 0; e < 8; e++){
        f32x4 ac1[2][4];
        #pragma unroll
        for (int i = 0; i < 2; i++)
            #pragma unroll
            for (int j = 0; j < 4; j++) ac1[i][j] = {0.f, 0.f, 0.f, 0.f};

        #pragma unroll                                     // xreg[ph] static
        for (int grp = 0; grp < 4; grp++){
            int g = e*6 + grp;
            const char* wbase = lds + WB2 + (g & 1)*24576;
            __builtin_amdgcn_s_setprio(1);
            #pragma unroll
            for (int c = 0; c < 3; c++){
                int ph = grp*3 + c;
                const char* wsl = wbase + c*8192 + q*2048;
                #pragma unroll
                for (int ni = 0; ni < 4; ni++){
                    bf16x8 bf = *(const bf16x8*)(wsl + (wc*64 + ni*16 + lr)*16);
                    ac1[0][ni] = __builtin_amdgcn_mfma_f32_16x16x32_bf16(xreg[ph][0], bf, ac1[0][ni], 0, 0, 0);
                    ac1[1][ni] = __builtin_amdgcn_mfma_f32_16x16x32_bf16(xreg[ph][1], bf, ac1[1][ni], 0, 0, 0);
                }
            }
            __builtin_amdgcn_s_setprio(0);
            if (grp == 3){
                // h = relu(ac1 + b1) -> Hs (XOR-swizzled)
                #pragma unroll
                for (int mi = 0; mi < 2; mi++)
                    #pragma unroll
                    for (int ni = 0; ni < 4; ni++){
                        int col = wc*64 + ni*16 + lr;
                        float b1v = bf2f(b1L[e*128 + col]);
                        #pragma unroll
                        for (int j = 0; j < 4; j++){
                            int row = wr*32 + mi*16 + q*4 + j;
                            *(u16*)(HsB + row*256 + ((col*2) ^ ((row & 7) << 4)))
                                = f2bf(fmaxf(ac1[mi][ni][j] + b1v, 0.f));
                        }
                    }
                asm volatile("s_waitcnt lgkmcnt(0)" ::: "memory");
            }
            __builtin_amdgcn_sched_barrier(0);
            __builtin_amdgcn_s_barrier();                  // slot reads + Hs writes done
            {
                int gn = g + 2;
                if (gn < 48){
                    WGROUP_STAGE2(gn, gn & 1);
                    asm volatile("s_waitcnt vmcnt(3)" ::: "memory");   // g+1 landed
                } else {
                    asm volatile("s_waitcnt vmcnt(0)" ::: "memory");
                }
            }
            __builtin_amdgcn_s_barrier();                  // next group + Hs visible
            __builtin_amdgcn_sched_barrier(0);
        }

        f32x4 ac2[2][4];
        #pragma unroll
        for (int i = 0; i < 2; i++)
            #pragma unroll
            for (int j = 0; j < 4; j++) ac2[i][j] = {0.f, 0.f, 0.f, 0.f};

        #pragma unroll 1
        for (int grp = 0; grp < 2; grp++){
            int g = e*6 + 4 + grp;
            const char* wbase = lds + WB2 + (g & 1)*24576;
            #pragma unroll
            for (int c = 0; c < 2; c++){
                int p2 = grp*2 + c;
                const char* wsl = wbase + c*8192 + q*2048;
                int cb = p2*64 + q*16;
                int rowA = wr*32 + lr;
                int rowB = wr*32 + 16 + lr;
                bf16x8 af0 = *(const bf16x8*)(HsB + rowA*256 + (cb ^ ((rowA & 7) << 4)));
                bf16x8 af1 = *(const bf16x8*)(HsB + rowB*256 + (cb ^ ((rowB & 7) << 4)));
                __builtin_amdgcn_s_setprio(1);
                #pragma unroll
                for (int ni = 0; ni < 4; ni++){
                    bf16x8 bf = *(const bf16x8*)(wsl + (wc*64 + ni*16 + lr)*16);
                    ac2[0][ni] = __builtin_amdgcn_mfma_f32_16x16x32_bf16(af0, bf, ac2[0][ni], 0, 0, 0);
                    ac2[1][ni] = __builtin_amdgcn_mfma_f32_16x16x32_bf16(af1, bf, ac2[1][ni], 0, 0, 0);
                }
                __builtin_amdgcn_s_setprio(0);
            }
            __builtin_amdgcn_sched_barrier(0);
            __builtin_amdgcn_s_barrier();                  // slot reads done
            {
                int gn = g + 2;
                if (gn < 48){
                    WGROUP_STAGE2(gn, gn & 1);
                    asm volatile("s_waitcnt vmcnt(3)" ::: "memory");
                } else {
                    asm volatile("s_waitcnt vmcnt(0)" ::: "memory");
                }
            }
            __builtin_amdgcn_s_barrier();
            __builtin_amdgcn_sched_barrier(0);
        }
        // fused += gw[:,e] * (eo + b2)
        #pragma unroll
        for (int mi = 0; mi < 2; mi++){
            f32x4 gwv = *(const f32x4*)(lds + GWT2 + e*512 + (wr*32 + mi*16 + q*4)*4);
            #pragma unroll
            for (int ni = 0; ni < 4; ni++){
                int col = wc*64 + ni*16 + lr;
                float b2v = bf2f(b2L[e*128 + col]);
                #pragma unroll
                for (int j = 0; j < 4; j++)
                    fus[mi][ni][j] += gwv[j] * (ac2[mi][ni][j] + b2v);
            }
        }
    }
#undef WGROUP_STAGE2

    __builtin_amdgcn_sched_barrier(0);
    __builtin_amdgcn_s_barrier();                      // all Hs(h7) reads done
    // fused -> Hs (bf16, XOR-swizzled)
    #pragma unroll
    for (int mi = 0; mi < 2; mi++)
        #pragma unroll
        for (int ni = 0; ni < 4; ni++){
            int col = wc*64 + ni*16 + lr;
            #pragma unroll
            for (int j = 0; j < 4; j++){
                int row = wr*32 + mi*16 + q*4 + j;
                *(u16*)(HsB + row*256 + ((col*2) ^ ((row & 7) << 4))) = f2bf(fus[mi][ni][j]);
            }
        }
    asm volatile("s_waitcnt lgkmcnt(0)" ::: "memory");
    __builtin_amdgcn_sched_barrier(0);
    __builtin_amdgcn_s_barrier();

    // ---- penult = relu(fused @ pre_w + pre_b): wave wid -> rows wid*16..+16 ----
    f32x4 ap[4];
    #pragma unroll
    for (int i = 0; i < 4; i++) ap[i] = {0.f, 0.f, 0.f, 0.f};
    #pragma unroll
    for (int kt = 0; kt < 4; kt++){
        int row = wid*16 + lr;
        int cb = kt*64 + q*16;
        bf16x8 af = *(const bf16x8*)(HsB + row*256 + (cb ^ ((row & 7) << 4)));
        #pragma unroll
        for (int ni = 0; ni < 4; ni++){
            bf16x8 bf = *(const bf16x8*)(prwT + (size_t)(ni*16 + lr)*128 + kt*32 + q*8);
            ap[ni] = __builtin_amdgcn_mfma_f32_16x16x32_bf16(af, bf, ap[ni], 0, 0, 0);
        }
    }
    float* Pen = (float*)(lds + WB2);   // [128][68], WB region dead
    #pragma unroll
    for (int ni = 0; ni < 4; ni++){
        int col = ni*16 + lr;
        float pbv = pre_b[col];
        #pragma unroll
        for (int j = 0; j < 4; j++){
            int row = wid*16 + q*4 + j;
            Pen[row*68 + col] = fmaxf(ap[ni][j] + pbv, 0.f);
        }
    }
    asm volatile("s_waitcnt lgkmcnt(0)" ::: "memory");
    __builtin_amdgcn_sched_barrier(0);
    __builtin_amdgcn_s_barrier();
    // ---- head ----
    if (tid < 256){
        int r = tid >> 1, c = tid & 1;
        float s = head_b[c];
        #pragma unroll 8
        for (int k = 0; k < 64; k++) s += Pen[r*68 + k] * head_w[k*2 + c];
        out[(size_t)(blk*128 + r)*2 + c] = s;
    }
}

extern "C" void kernel_launch(void* const* d_in, const int* in_sizes, int n_in,
                              void* d_out, int out_size, void* d_ws, size_t ws_size,
                              hipStream_t stream) {
    const float* ft     = (const float*)d_in[0];
    const float* fa     = (const float*)d_in[1];
    const float* fv     = (const float*)d_in[2];
    const float* proj_w = (const float*)d_in[3];
    const float* proj_b = (const float*)d_in[4];
    const float* exp_w1 = (const float*)d_in[5];
    const float* exp_b1 = (const float*)d_in[6];
    const float* exp_w2 = (const float*)d_in[7];
    const float* exp_b2 = (const float*)d_in[8];
    const float* gate_w = (const float*)d_in[9];
    const float* gate_b = (const float*)d_in[10];
    const float* pre_w  = (const float*)d_in[11];
    const float* pre_b  = (const float*)d_in[12];
    const float* head_w = (const float*)d_in[13];
    const float* head_b = (const float*)d_in[14];
    float* out = (float*)d_out;

    u16* pimg  = (u16*)d_ws;                      // 294912
    u16* w1img = pimg + 294912;                   // 393216
    u16* w2img = w1img + 393216;                  // 131072
    u16* prwT  = w2img + 131072;                  // 8192
    u16* gwimg = prwT + 8192;                     // 6144

    cast_weights_kernel<<<3256, 256, 0, stream>>>(proj_w, exp_w1, exp_w2, pre_w, gate_w,
                                                  pimg, w1img, w2img, prwT, gwimg);
    fused_kernel<<<256, 512, 0, stream>>>(ft, fa, fv, pimg, proj_b,
                                          w1img, w2img, prwT, gwimg,
                                          gate_b, exp_b1, exp_b2,
                                          pre_b, head_w, head_b, out);
}